// Round 5
// baseline (503.324 us; speedup 1.0000x reference)
//
#include <hip/hip_runtime.h>
#include <hip/hip_bf16.h>

typedef unsigned short u16;
typedef unsigned int u32;
typedef __attribute__((ext_vector_type(8))) short short8;
typedef __attribute__((ext_vector_type(4))) float f32x4;

#define B_ 4
#define T_ 2048
#define D_ 1024
#define H_ 16
#define HS_ 64
#define BT (B_*T_)

__device__ __forceinline__ float bf2f(u16 b){ union{u32 u; float f;} v; v.u=((u32)b)<<16; return v.f; }
__device__ __forceinline__ u16 f2bf(float f){
    __hip_bfloat16 h = __float2bfloat16(f);
    union{__hip_bfloat16 h; u16 u;} v; v.h = h; return v.u;
}
// split f32 into hi/lo bf16: x ~= hi + lo
__device__ __forceinline__ void split2(float x, u16& h, u16& l){
    u16 hb = f2bf(x);
    float fh = bf2f(hb);
    h = hb; l = f2bf(x - fh);
}
union U4 { u16 s[4]; uint2 v; };
union S8 { u16 s[8]; short8 v; };

// async global->LDS, 16B per lane; LDS dest wave-linear (base + lane*16)
#define GLD16(g,l) __builtin_amdgcn_global_load_lds( \
    (__attribute__((address_space(1))) void*)(u16*)(g), \
    (__attribute__((address_space(3))) void*)(l), 16, 0, 0)

// XOR-swizzled offset into a row-major [R][64]-u16 LDS tile, 16B-chunk granularity.
__device__ __forceinline__ int swz(int row, int col){
    return row*64 + (((col>>3) ^ (row&7))<<3) + (col&7);
}
// chunk-swizzle for the GEMM [128][32]-u16 tiles (64B rows, 4 x 16B chunks).
// Proven: SQ_LDS_BANK_CONFLICT 12.6M -> 0 (round 4).
#define FCHK(r) (((r)>>1)&3)

// DPP cross-lane move within a 16-lane row
#define DPPMV(x, ctrl) __int_as_float(__builtin_amdgcn_update_dpp(0, __float_as_int(x), (ctrl), 0xF, 0xF, true))

// ---- grid-stride f32 -> (hi,lo) bf16 split, 8 elems/thread/iter ----
__global__ __launch_bounds__(256) void split_f32(const float* __restrict__ src,
                                                 u16* __restrict__ dh, u16* __restrict__ dl,
                                                 int n8)
{
    int i = blockIdx.x*256 + threadIdx.x;
    const int stride = gridDim.x*256;
    for (; i < n8; i += stride){
        float4 a = *(const float4*)(src + (size_t)i*8);
        float4 b = *(const float4*)(src + (size_t)i*8 + 4);
        S8 hh, ll;
        split2(a.x, hh.s[0], ll.s[0]); split2(a.y, hh.s[1], ll.s[1]);
        split2(a.z, hh.s[2], ll.s[2]); split2(a.w, hh.s[3], ll.s[3]);
        split2(b.x, hh.s[4], ll.s[4]); split2(b.y, hh.s[5], ll.s[5]);
        split2(b.z, hh.s[6], ll.s[6]); split2(b.w, hh.s[7], ll.s[7]);
        *(short8*)(dh + (size_t)i*8) = hh.v;
        *(short8*)(dl + (size_t)i*8) = ll.v;
    }
}

// ---- pack: Wt[n][d] (split hi/lo) = W_z[h][d][e], n = z*1024 + h*64 + e ----
__global__ __launch_bounds__(256) void pack_w(const float* __restrict__ Wq,
                                              const float* __restrict__ Wk,
                                              const float* __restrict__ Wv,
                                              u16* __restrict__ Wth,
                                              u16* __restrict__ Wtl)
{
    __shared__ float Tl[64*68];
    const int h = blockIdx.x, dt = blockIdx.y, z = blockIdx.z;
    const float* src = (z==0) ? Wq : ((z==1) ? Wk : Wv);
    const int t = threadIdx.x;
    const int d0 = dt*64;
    #pragma unroll
    for (int i=0;i<4;++i){
        int ci = t + 256*i;
        int dr = ci>>4, ec = ci&15;
        float4 v = *(const float4*)(src + ((size_t)h*D_ + d0+dr)*HS_ + ec*4);
        *(float4*)(Tl + dr*68 + ec*4) = v;
    }
    __syncthreads();
    #pragma unroll
    for (int i=0;i<4;++i){
        int ci = t + 256*i;
        int e = ci>>4, dc = ci&15;
        U4 hh, ll;
        #pragma unroll
        for (int j=0;j<4;++j){
            float f = Tl[(dc*4+j)*68 + e];
            split2(f, hh.s[j], ll.s[j]);
        }
        int n = z*D_ + h*HS_ + e;
        *(uint2*)(Wth + (size_t)n*D_ + d0 + dc*4) = hh.v;
        *(uint2*)(Wtl + (size_t)n*D_ + d0 + dc*4) = ll.v;
    }
}

// ---- QKV GEMM: qkv[t][col] = x[t][:]·Wt[col][:], col in [0,3072) ----
// PS=true: A staged from pre-split xh/xl via GLD16 (pure async, zero VALU/ds_write
// in loop); q written pre-split. PS=false: round-4 path (bit-identical output).
template<bool PS>
__global__ __launch_bounds__(256) void gemm_qkv(const float* __restrict__ x,
                                                const u16* __restrict__ xh, const u16* __restrict__ xl,
                                                const u16* __restrict__ Wth,
                                                const u16* __restrict__ Wtl,
                                                float* __restrict__ qo,
                                                u16* __restrict__ qho, u16* __restrict__ qlo,
                                                u16* __restrict__ kho, u16* __restrict__ klo,
                                                u16* __restrict__ vth, u16* __restrict__ vtl)
{
    __shared__ u16 Ash[128*32], Asl[128*32];
    __shared__ u16 Bsh[128*32], Bsl[128*32];
    const int n0 = blockIdx.x*128, m0 = blockIdx.y*128;
    const int t = threadIdx.x;
    const int w = t>>6, lane = t&63, quad = lane>>4, l16 = lane&15;
    const int wm = (w>>1)*64, wn = (w&1)*64;
    f32x4 acc[4][4];
    #pragma unroll
    for (int i=0;i<4;++i)
        #pragma unroll
        for (int j=0;j<4;++j) acc[i][j] = (f32x4){0.f,0.f,0.f,0.f};
    for (int kt=0; kt<32; ++kt){
        const int k0 = kt*32;
        #pragma unroll
        for (int i=0;i<2;++i){           // B: async 16B chunks, pre-swizzled source
            int ci = t + 256*i;
            int row = ci>>2, c = ci&3;
            int cs = c ^ FCHK(row);
            GLD16(Wth + (size_t)(n0+row)*D_ + k0 + cs*8, Bsh + ci*8);
            GLD16(Wtl + (size_t)(n0+row)*D_ + k0 + cs*8, Bsl + ci*8);
        }
        if constexpr(PS){
            #pragma unroll
            for (int i=0;i<2;++i){       // A: async too (pre-split x)
                int ci = t + 256*i;
                int row = ci>>2, c = ci&3;
                int cs = c ^ FCHK(row);
                GLD16(xh + (size_t)(m0+row)*D_ + k0 + cs*8, Ash + ci*8);
                GLD16(xl + (size_t)(m0+row)*D_ + k0 + cs*8, Asl + ci*8);
            }
        } else {
            #pragma unroll
            for (int i=0;i<4;++i){       // A: f32 load + split, swizzled ds_write
                int ci = t + 256*i;
                int row = ci>>3, c4 = ci&7;
                float4 av = *(const float4*)(x + (size_t)(m0+row)*D_ + k0 + c4*4);
                U4 hh, ll;
                split2(av.x, hh.s[0], ll.s[0]); split2(av.y, hh.s[1], ll.s[1]);
                split2(av.z, hh.s[2], ll.s[2]); split2(av.w, hh.s[3], ll.s[3]);
                int off = row*32 + ((((c4>>1) ^ FCHK(row))<<3) | ((c4&1)<<2));
                *(uint2*)(Ash + off) = hh.v;
                *(uint2*)(Asl + off) = ll.v;
            }
        }
        __syncthreads();
        short8 afh[4], afl[4], bfh[4], bfl[4];
        #pragma unroll
        for (int mi=0;mi<4;++mi){
            const int rr = wm+mi*16+l16;
            const int off = rr*32 + ((quad ^ FCHK(rr))<<3);
            afh[mi] = *(const short8*)(Ash + off);
            afl[mi] = *(const short8*)(Asl + off);
        }
        #pragma unroll
        for (int ni=0;ni<4;++ni){
            const int rr = wn+ni*16+l16;
            const int off = rr*32 + ((quad ^ FCHK(rr))<<3);
            bfh[ni] = *(const short8*)(Bsh + off);
            bfl[ni] = *(const short8*)(Bsl + off);
        }
        #pragma unroll
        for (int mi=0;mi<4;++mi)
            #pragma unroll
            for (int ni=0;ni<4;++ni){
                acc[mi][ni] = __builtin_amdgcn_mfma_f32_16x16x32_bf16(afh[mi], bfh[ni], acc[mi][ni], 0,0,0);
                acc[mi][ni] = __builtin_amdgcn_mfma_f32_16x16x32_bf16(afh[mi], bfl[ni], acc[mi][ni], 0,0,0);
                acc[mi][ni] = __builtin_amdgcn_mfma_f32_16x16x32_bf16(afl[mi], bfh[ni], acc[mi][ni], 0,0,0);
            }
        __syncthreads();
    }
    const int z = n0 >> 10;              // block-uniform (128 | 1024)
    if (z <= 1){
        if constexpr(PS){
            u16* dh = z ? kho : qho;
            u16* dl = z ? klo : qlo;
            #pragma unroll
            for (int ni=0;ni<4;++ni){
                const int nloc = (n0 & 1023) + wn + ni*16 + l16;
                #pragma unroll
                for (int mi=0;mi<4;++mi){
                    const int row = m0 + wm + mi*16 + quad*4;
                    #pragma unroll
                    for (int r=0;r<4;++r){
                        u16 hh, ll; split2(acc[mi][ni][r], hh, ll);
                        dh[(size_t)(row+r)*D_ + nloc] = hh;
                        dl[(size_t)(row+r)*D_ + nloc] = ll;
                    }
                }
            }
        } else {
            if (z == 0){
                #pragma unroll
                for (int ni=0;ni<4;++ni){
                    const int nloc = (n0 & 1023) + wn + ni*16 + l16;
                    #pragma unroll
                    for (int mi=0;mi<4;++mi){
                        const int row = m0 + wm + mi*16 + quad*4;
                        #pragma unroll
                        for (int r=0;r<4;++r)
                            qo[(size_t)(row+r)*D_ + nloc] = acc[mi][ni][r];
                    }
                }
            } else {
                #pragma unroll
                for (int ni=0;ni<4;++ni){
                    const int nloc = (n0 & 1023) + wn + ni*16 + l16;
                    #pragma unroll
                    for (int mi=0;mi<4;++mi){
                        const int row = m0 + wm + mi*16 + quad*4;
                        #pragma unroll
                        for (int r=0;r<4;++r){
                            u16 hh, ll; split2(acc[mi][ni][r], hh, ll);
                            kho[(size_t)(row+r)*D_ + nloc] = hh;
                            klo[(size_t)(row+r)*D_ + nloc] = ll;
                        }
                    }
                }
            }
        }
    } else {
        #pragma unroll
        for (int ni=0;ni<4;++ni){
            const int nloc = (n0 & 1023) + wn + ni*16 + l16;
            const int hloc = nloc>>6, e = nloc&63;
            #pragma unroll
            for (int mi=0;mi<4;++mi){
                const int rowb = m0 + wm + mi*16 + quad*4;   // multiple of 4
                const int bidx = rowb >> 11, tloc = rowb & 2047;
                U4 hh, ll;
                #pragma unroll
                for (int r=0;r<4;++r) split2(acc[mi][ni][r], hh.s[r], ll.s[r]);
                const size_t adr = ((size_t)((bidx*16 + hloc)*64 + e))*T_ + tloc;
                *(uint2*)(vth + adr) = hh.v;
                *(uint2*)(vtl + adr) = ll.v;
            }
        }
    }
}

// ---- causal flash attention; paired q-tiles (qi=15-x then x), 512 blocks,
// 2 blocks/CU, XCD-grouped K/V sharing; (512,2) launch bounds (min-BLOCKS/CU
// semantics, round-1 proven). PS=true: q read pre-split, att written pre-split. ----
template<bool PS>
__global__ __launch_bounds__(512, 2) void attn(const float* __restrict__ qf,
                                            const u16* __restrict__ qh, const u16* __restrict__ ql,
                                            const u16* __restrict__ kh, const u16* __restrict__ kl,
                                            const u16* __restrict__ vth, const u16* __restrict__ vtl,
                                            float* __restrict__ att,
                                            u16* __restrict__ atth, u16* __restrict__ attl)
{
    __shared__ u16 Ksh[64*64], Ksl[64*64];   // [kv][e], swizzled (16 KB)
    __shared__ u16 Vsh[64*64], Vsl[64*64];   // [e][kv], swizzled (16 KB)
    __shared__ u16 Pb[8*32*64];              // per-wave [32][64]: hi rows 0-15, lo rows 16-31 (32 KB)
    const int x = blockIdx.y & 7;            // q-pair index (XCD-grouped remap)
    const int bh = (blockIdx.x << 3) | (blockIdx.y >> 3);
    const int b = bh >> 4, h = bh & 15;
    const int t = threadIdx.x;
    const int w = t>>6, lane = t&63, quad = lane>>4, l16 = lane&15;

    u16* Pm = Pb + w*2048;

    // staging geometry: 512 threads = 64 rows x 8 chunks, 1 uint4/thread/array
    const int srow = t>>3, sc = t&7;
    const int slo = swz(srow, sc*8);
    uint4 pkh, pkl, pvh, pvl;                // register prefetch
    {   // prime kv tile 0 (segment 0)
        const size_t gk = ((size_t)(b*T_ + srow))*D_ + h*64 + sc*8;
        pkh = *(const uint4*)(kh + gk);
        pkl = *(const uint4*)(kl + gk);
        const size_t gv = ((size_t)(bh*64 + srow))*T_ + sc*8;
        pvh = *(const uint4*)(vth + gv);
        pvl = *(const uint4*)(vtl + gv);
    }

    #pragma unroll 1
    for (int seg=0; seg<2; ++seg){
        const int qi = seg ? x : (15 - x);   // heavy segment first
        const int qrow = qi*128 + w*16;      // wave's absolute q base

        short8 qh_[2], ql_[2];
        if constexpr(PS){
            const size_t qb = ((size_t)(b*T_ + qrow + l16))*D_ + h*64;
            #pragma unroll
            for (int ks=0;ks<2;++ks){
                qh_[ks] = *(const short8*)(qh + qb + ks*32 + quad*8);
                ql_[ks] = *(const short8*)(ql + qb + ks*32 + quad*8);
            }
        } else {
            const float* qp = qf + ((size_t)(b*T_ + qrow + l16))*D_ + h*64;
            #pragma unroll
            for (int ks=0;ks<2;++ks){
                float4 a0 = *(const float4*)(qp + ks*32 + quad*8);
                float4 a1 = *(const float4*)(qp + ks*32 + quad*8 + 4);
                S8 hh, ll;
                split2(a0.x, hh.s[0], ll.s[0]); split2(a0.y, hh.s[1], ll.s[1]);
                split2(a0.z, hh.s[2], ll.s[2]); split2(a0.w, hh.s[3], ll.s[3]);
                split2(a1.x, hh.s[4], ll.s[4]); split2(a1.y, hh.s[5], ll.s[5]);
                split2(a1.z, hh.s[6], ll.s[6]); split2(a1.w, hh.s[7], ll.s[7]);
                qh_[ks] = hh.v; ql_[ks] = ll.v;
            }
        }
        f32x4 o[4];
        #pragma unroll
        for (int i=0;i<4;++i) o[i] = (f32x4){0.f,0.f,0.f,0.f};
        float m_i[4], l_i[4];
        #pragma unroll
        for (int r=0;r<4;++r){ m_i[r] = -INFINITY; l_i[r] = 0.f; }

        const int kvT = 2*qi + 2;
        for (int kvt=0; kvt<kvT; ++kvt){
            __syncthreads();                 // prev-iter readers done
            *(uint4*)(Ksh + slo) = pkh;
            *(uint4*)(Ksl + slo) = pkl;
            *(uint4*)(Vsh + slo) = pvh;
            *(uint4*)(Vsl + slo) = pvl;
            // prefetch next tile; across the segment boundary prefetch seg1 tile 0
            const int nk = (kvt+1 < kvT) ? (kvt+1) : ((seg==0) ? 0 : -1);
            if (nk >= 0){
                const size_t gk = ((size_t)(b*T_ + nk*64 + srow))*D_ + h*64 + sc*8;
                pkh = *(const uint4*)(kh + gk);
                pkl = *(const uint4*)(kl + gk);
                const size_t gv = ((size_t)(bh*64 + srow))*T_ + nk*64 + sc*8;
                pvh = *(const uint4*)(vth + gv);
                pvl = *(const uint4*)(vtl + gv);
            }
            __syncthreads();

            float s[4][4];
            __builtin_amdgcn_s_setprio(1);
            #pragma unroll
            for (int ni=0;ni<4;++ni){
                f32x4 sa = (f32x4){0.f,0.f,0.f,0.f};
                const int row = ni*16 + l16;
                #pragma unroll
                for (int ks=0;ks<2;++ks){
                    const int co = swz(row, ks*32 + quad*8);
                    short8 k8h = *(const short8*)(Ksh + co);
                    short8 k8l = *(const short8*)(Ksl + co);
                    sa = __builtin_amdgcn_mfma_f32_16x16x32_bf16(qh_[ks], k8h, sa, 0,0,0);
                    sa = __builtin_amdgcn_mfma_f32_16x16x32_bf16(qh_[ks], k8l, sa, 0,0,0);
                    sa = __builtin_amdgcn_mfma_f32_16x16x32_bf16(ql_[ks], k8h, sa, 0,0,0);
                }
                #pragma unroll
                for (int r=0;r<4;++r) s[ni][r] = sa[r]*0.125f;
            }
            __builtin_amdgcn_s_setprio(0);
            // causal mask iff tile max col can exceed wave MIN row
            if (kvt*64 + 63 > qrow){
                #pragma unroll
                for (int ni=0;ni<4;++ni){
                    const int colabs = kvt*64 + ni*16 + l16;
                    #pragma unroll
                    for (int r=0;r<4;++r){
                        const int rowabs = qrow + quad*4 + r;
                        if (colabs > rowabs) s[ni][r] = -INFINITY;
                    }
                }
            }
            float alpha[4];
            #pragma unroll
            for (int r=0;r<4;++r){
                float rm = fmaxf(fmaxf(s[0][r],s[1][r]), fmaxf(s[2][r],s[3][r]));
                rm = fmaxf(rm, DPPMV(rm, 0xB1));   // quad_perm xor1
                rm = fmaxf(rm, DPPMV(rm, 0x4E));   // quad_perm xor2
                rm = fmaxf(rm, DPPMV(rm, 0x124));  // row_ror:4
                rm = fmaxf(rm, DPPMV(rm, 0x128));  // row_ror:8
                const float mnew = fmaxf(m_i[r], rm);
                alpha[r] = __expf(m_i[r] - mnew);
                m_i[r] = mnew;
                #pragma unroll
                for (int ni=0;ni<4;++ni) s[ni][r] = __expf(s[ni][r] - mnew);  // in place
                float rs = s[0][r]+s[1][r]+s[2][r]+s[3][r];
                rs += DPPMV(rs, 0xB1);
                rs += DPPMV(rs, 0x4E);
                rs += DPPMV(rs, 0x124);
                rs += DPPMV(rs, 0x128);
                l_i[r] = l_i[r]*alpha[r] + rs;
            }
            #pragma unroll
            for (int ni=0;ni<4;++ni)
                #pragma unroll
                for (int r=0;r<4;++r) o[ni][r] *= alpha[r];

            // ---- P: split once, write hi rows 0-15 + lo rows 16-31, one wait, read both ----
            u16 ph[4][4], pl[4][4];
            #pragma unroll
            for (int ni=0;ni<4;++ni)
                #pragma unroll
                for (int r=0;r<4;++r)
                    split2(s[ni][r], ph[ni][r], pl[ni][r]);
            #pragma unroll
            for (int ni=0;ni<4;++ni)
                #pragma unroll
                for (int r=0;r<4;++r){
                    Pm[swz(quad*4+r,      ni*16 + l16)] = ph[ni][r];
                    Pm[swz(16 + quad*4+r, ni*16 + l16)] = pl[ni][r];
                }
            __asm__ volatile("s_waitcnt lgkmcnt(0)" ::: "memory");
            short8 pah[2], pal[2];
            #pragma unroll
            for (int ks=0;ks<2;++ks){
                pah[ks] = *(const short8*)(Pm + swz(l16,      ks*32 + quad*8));
                pal[ks] = *(const short8*)(Pm + swz(16 + l16, ks*32 + quad*8));
            }

            __builtin_amdgcn_s_setprio(1);
            #pragma unroll
            for (int ni=0;ni<4;++ni){
                const int row = ni*16 + l16;
                #pragma unroll
                for (int ks=0;ks<2;++ks){
                    const int co = swz(row, ks*32 + quad*8);
                    short8 v8h = *(const short8*)(Vsh + co);
                    short8 v8l = *(const short8*)(Vsl + co);
                    o[ni] = __builtin_amdgcn_mfma_f32_16x16x32_bf16(pah[ks], v8h, o[ni], 0,0,0);
                    o[ni] = __builtin_amdgcn_mfma_f32_16x16x32_bf16(pah[ks], v8l, o[ni], 0,0,0);
                    o[ni] = __builtin_amdgcn_mfma_f32_16x16x32_bf16(pal[ks], v8h, o[ni], 0,0,0);
                }
            }
            __builtin_amdgcn_s_setprio(0);
        }
        const size_t ob = (size_t)(b*T_ + qrow);
        #pragma unroll
        for (int ni=0;ni<4;++ni){
            const int col = h*64 + ni*16 + l16;
            #pragma unroll
            for (int r=0;r<4;++r){
                const float v = o[ni][r] / l_i[r];
                const size_t idx = (ob + quad*4 + r)*D_ + col;
                if constexpr(PS){
                    u16 hh, ll; split2(v, hh, ll);
                    atth[idx] = hh; attl[idx] = ll;
                } else {
                    att[idx] = v;
                }
            }
        }
    }
}

// ---- out-proj GEMM. PS=true: A=atth/attl, B=Wph/Wpl, all GLD16.
// PS=false: round-4 f32-staged path. ----
template<bool PS>
__global__ __launch_bounds__(256) void gemm_bt(const float* __restrict__ A,
                                               const u16* __restrict__ Ath, const u16* __restrict__ Atl,
                                               const float* __restrict__ Bt,
                                               const u16* __restrict__ Bth, const u16* __restrict__ Btl,
                                               float* __restrict__ C,
                                               const float* __restrict__ bias,
                                               int M, int N, int K)
{
    __shared__ u16 Ash[128*32], Asl[128*32];
    __shared__ u16 Bsh[128*32], Bsl[128*32];
    const int n0 = blockIdx.x*128, m0 = blockIdx.y*128;
    const int t = threadIdx.x;
    const int w = t>>6, lane = t&63, quad = lane>>4, l16 = lane&15;
    const int wm = (w>>1)*64, wn = (w&1)*64;
    f32x4 acc[4][4];
    #pragma unroll
    for (int i=0;i<4;++i)
        #pragma unroll
        for (int j=0;j<4;++j) acc[i][j] = (f32x4){0.f,0.f,0.f,0.f};
    const int kT = K >> 5;
    for (int kt=0; kt<kT; ++kt){
        const int k0 = kt*32;
        if constexpr(PS){
            #pragma unroll
            for (int i=0;i<2;++i){
                int ci = t + 256*i;
                int row = ci>>2, c = ci&3;
                int cs = c ^ FCHK(row);
                GLD16(Ath + (size_t)(m0+row)*K + k0 + cs*8, Ash + ci*8);
                GLD16(Atl + (size_t)(m0+row)*K + k0 + cs*8, Asl + ci*8);
                GLD16(Bth + (size_t)(n0+row)*K + k0 + cs*8, Bsh + ci*8);
                GLD16(Btl + (size_t)(n0+row)*K + k0 + cs*8, Bsl + ci*8);
            }
        } else {
            #pragma unroll
            for (int i=0;i<4;++i){
                int ci = t + 256*i;
                int row = ci>>3, c4 = ci&7;
                float4 av = *(const float4*)(A  + (size_t)(m0+row)*K + k0 + c4*4);
                float4 bv = *(const float4*)(Bt + (size_t)(n0+row)*K + k0 + c4*4);
                U4 ah, al, bh, bl;
                split2(av.x, ah.s[0], al.s[0]); split2(av.y, ah.s[1], al.s[1]);
                split2(av.z, ah.s[2], al.s[2]); split2(av.w, ah.s[3], al.s[3]);
                split2(bv.x, bh.s[0], bl.s[0]); split2(bv.y, bh.s[1], bl.s[1]);
                split2(bv.z, bh.s[2], bl.s[2]); split2(bv.w, bh.s[3], bl.s[3]);
                int off = row*32 + ((((c4>>1) ^ FCHK(row))<<3) | ((c4&1)<<2));
                *(uint2*)(Ash + off) = ah.v;
                *(uint2*)(Asl + off) = al.v;
                *(uint2*)(Bsh + off) = bh.v;
                *(uint2*)(Bsl + off) = bl.v;
            }
        }
        __syncthreads();
        short8 afh[4], afl[4], bfh[4], bfl[4];
        #pragma unroll
        for (int mi=0;mi<4;++mi){
            const int rr = wm+mi*16+l16;
            const int off = rr*32 + ((quad ^ FCHK(rr))<<3);
            afh[mi] = *(const short8*)(Ash + off);
            afl[mi] = *(const short8*)(Asl + off);
        }
        #pragma unroll
        for (int ni=0;ni<4;++ni){
            const int rr = wn+ni*16+l16;
            const int off = rr*32 + ((quad ^ FCHK(rr))<<3);
            bfh[ni] = *(const short8*)(Bsh + off);
            bfl[ni] = *(const short8*)(Bsl + off);
        }
        #pragma unroll
        for (int mi=0;mi<4;++mi)
            #pragma unroll
            for (int ni=0;ni<4;++ni){
                acc[mi][ni] = __builtin_amdgcn_mfma_f32_16x16x32_bf16(afh[mi], bfh[ni], acc[mi][ni], 0,0,0);
                acc[mi][ni] = __builtin_amdgcn_mfma_f32_16x16x32_bf16(afh[mi], bfl[ni], acc[mi][ni], 0,0,0);
                acc[mi][ni] = __builtin_amdgcn_mfma_f32_16x16x32_bf16(afl[mi], bfh[ni], acc[mi][ni], 0,0,0);
            }
        __syncthreads();
    }
    #pragma unroll
    for (int ni=0;ni<4;++ni){
        const int col = n0 + wn + ni*16 + l16;
        const float bv = bias ? bias[col] : 0.f;
        #pragma unroll
        for (int mi=0;mi<4;++mi){
            const int row = m0 + wm + mi*16 + quad*4;
            #pragma unroll
            for (int r=0;r<4;++r)
                C[(size_t)(row+r)*N + col] = acc[mi][ni][r] + bv;
        }
    }
}

extern "C" void kernel_launch(void* const* d_in, const int* in_sizes, int n_in,
                              void* d_out, int out_size, void* d_ws, size_t ws_size,
                              hipStream_t stream)
{
    const float* x  = (const float*)d_in[0];
    const float* Wq = (const float*)d_in[1];
    const float* Wk = (const float*)d_in[2];
    const float* Wv = (const float*)d_in[3];
    const float* Wp = (const float*)d_in[4];
    const float* bp = (const float*)d_in[5];
    float* out = (float*)d_out;

    const size_t NE = (size_t)BT*D_;                  // 8.39M elems
    const size_t NEED = (10*NE + 2*(size_t)D_*D_)*2;  // 171,966,464 B

    if (ws_size >= NEED){
        // pre-split layout (172 MB)
        u16* xh   = (u16*)d_ws;
        u16* xl   = xh + NE;
        u16* qh   = xl + NE;
        u16* ql   = qh + NE;
        u16* kh   = ql + NE;
        u16* kl   = kh + NE;
        u16* vth  = kl + NE;
        u16* vtl  = vth + NE;
        u16* atth = vtl + NE;                 // [BT][1024] split pair
        u16* attl = atth + NE;
        u16* Wph  = attl + NE;                // [1024][1024] split pair
        u16* Wpl  = Wph + (size_t)D_*D_;
        // Wt aliases atth region (12.6 MB <= 16.8 MB): dead before attn writes atth
        u16* Wth  = atth;
        u16* Wtl  = Wth + (size_t)3072*D_;

        split_f32<<<1024, 256, 0, stream>>>(x,  xh,  xl,  (int)(NE/8));
        split_f32<<<512,  256, 0, stream>>>(Wp, Wph, Wpl, (int)(((size_t)D_*D_)/8));
        pack_w   <<<dim3(16,16,3), 256, 0, stream>>>(Wq, Wk, Wv, Wth, Wtl);
        gemm_qkv<true><<<dim3(24, BT/128), 256, 0, stream>>>(x, xh, xl, Wth, Wtl,
                                                             nullptr, qh, ql, kh, kl, vth, vtl);
        attn<true><<<dim3(T_/256, B_*H_), 512, 0, stream>>>(nullptr, qh, ql, kh, kl, vth, vtl,
                                                            nullptr, atth, attl);
        gemm_bt<true><<<dim3(8, BT/128), 256, 0, stream>>>(nullptr, atth, attl,
                                                           nullptr, Wph, Wpl,
                                                           out, bp, BT, D_, D_);
    } else {
        // round-4 fallback layout (134.2 MB)
        float* q   = (float*)d_ws;
        u16*  kh   = (u16*)(q + NE);
        u16*  kl   = kh + NE;
        u16*  vth  = kl + NE;
        u16*  vtl  = vth + NE;
        float* att = (float*)(vtl + NE);
        u16*  Wth  = (u16*)att;
        u16*  Wtl  = Wth + (size_t)3072*D_;

        pack_w   <<<dim3(16,16,3), 256, 0, stream>>>(Wq, Wk, Wv, Wth, Wtl);
        gemm_qkv<false><<<dim3(24, BT/128), 256, 0, stream>>>(x, nullptr, nullptr, Wth, Wtl,
                                                              q, nullptr, nullptr, kh, kl, vth, vtl);
        attn<false><<<dim3(T_/256, B_*H_), 512, 0, stream>>>(q, nullptr, nullptr, kh, kl, vth, vtl,
                                                             att, nullptr, nullptr);
        gemm_bt<false><<<dim3(8, BT/128), 256, 0, stream>>>(att, nullptr, nullptr,
                                                            Wp, nullptr, nullptr,
                                                            out, bp, BT, D_, D_);
    }
}

// Round 6
// 492.666 us; speedup vs baseline: 1.0216x; 1.0216x over previous
//
#include <hip/hip_runtime.h>
#include <hip/hip_bf16.h>

typedef unsigned short u16;
typedef unsigned int u32;
typedef __attribute__((ext_vector_type(8))) short short8;
typedef __attribute__((ext_vector_type(4))) float f32x4;

#define B_ 4
#define T_ 2048
#define D_ 1024
#define H_ 16
#define HS_ 64
#define BT (B_*T_)

__device__ __forceinline__ float bf2f(u16 b){ union{u32 u; float f;} v; v.u=((u32)b)<<16; return v.f; }
__device__ __forceinline__ u16 f2bf(float f){
    __hip_bfloat16 h = __float2bfloat16(f);
    union{__hip_bfloat16 h; u16 u;} v; v.h = h; return v.u;
}
// split f32 into hi/lo bf16: x ~= hi + lo
__device__ __forceinline__ void split2(float x, u16& h, u16& l){
    u16 hb = f2bf(x);
    float fh = bf2f(hb);
    h = hb; l = f2bf(x - fh);
}
union U4 { u16 s[4]; uint2 v; };
union S8 { u16 s[8]; short8 v; };

// async global->LDS, 16B per lane; LDS dest wave-linear (base + lane*16)
#define GLD16(g,l) __builtin_amdgcn_global_load_lds( \
    (__attribute__((address_space(1))) void*)(u16*)(g), \
    (__attribute__((address_space(3))) void*)(l), 16, 0, 0)

// XOR-swizzled offset into a row-major [R][64]-u16 LDS tile, 16B-chunk granularity.
__device__ __forceinline__ int swz(int row, int col){
    return row*64 + (((col>>3) ^ (row&7))<<3) + (col&7);
}
// chunk-swizzle for the GEMM [128][32]-u16 tiles (64B rows, 4 x 16B chunks).
// Proven: SQ_LDS_BANK_CONFLICT 12.6M -> 0 (round 4).
#define FCHK(r) (((r)>>1)&3)

// DPP cross-lane move within a 16-lane row
#define DPPMV(x, ctrl) __int_as_float(__builtin_amdgcn_update_dpp(0, __float_as_int(x), (ctrl), 0xF, 0xF, true))

// ---- grid-stride f32 -> (hi,lo) bf16 split, 8 elems/thread/iter ----
__global__ __launch_bounds__(256) void split_f32(const float* __restrict__ src,
                                                 u16* __restrict__ dh, u16* __restrict__ dl,
                                                 int n8)
{
    int i = blockIdx.x*256 + threadIdx.x;
    const int stride = gridDim.x*256;
    for (; i < n8; i += stride){
        float4 a = *(const float4*)(src + (size_t)i*8);
        float4 b = *(const float4*)(src + (size_t)i*8 + 4);
        S8 hh, ll;
        split2(a.x, hh.s[0], ll.s[0]); split2(a.y, hh.s[1], ll.s[1]);
        split2(a.z, hh.s[2], ll.s[2]); split2(a.w, hh.s[3], ll.s[3]);
        split2(b.x, hh.s[4], ll.s[4]); split2(b.y, hh.s[5], ll.s[5]);
        split2(b.z, hh.s[6], ll.s[6]); split2(b.w, hh.s[7], ll.s[7]);
        *(short8*)(dh + (size_t)i*8) = hh.v;
        *(short8*)(dl + (size_t)i*8) = ll.v;
    }
}

// ---- pack: Wt[n][d] (split hi/lo) = W_z[h][d][e], n = z*1024 + h*64 + e ----
__global__ __launch_bounds__(256) void pack_w(const float* __restrict__ Wq,
                                              const float* __restrict__ Wk,
                                              const float* __restrict__ Wv,
                                              u16* __restrict__ Wth,
                                              u16* __restrict__ Wtl)
{
    __shared__ float Tl[64*68];
    const int h = blockIdx.x, dt = blockIdx.y, z = blockIdx.z;
    const float* src = (z==0) ? Wq : ((z==1) ? Wk : Wv);
    const int t = threadIdx.x;
    const int d0 = dt*64;
    #pragma unroll
    for (int i=0;i<4;++i){
        int ci = t + 256*i;
        int dr = ci>>4, ec = ci&15;
        float4 v = *(const float4*)(src + ((size_t)h*D_ + d0+dr)*HS_ + ec*4);
        *(float4*)(Tl + dr*68 + ec*4) = v;
    }
    __syncthreads();
    #pragma unroll
    for (int i=0;i<4;++i){
        int ci = t + 256*i;
        int e = ci>>4, dc = ci&15;
        U4 hh, ll;
        #pragma unroll
        for (int j=0;j<4;++j){
            float f = Tl[(dc*4+j)*68 + e];
            split2(f, hh.s[j], ll.s[j]);
        }
        int n = z*D_ + h*HS_ + e;
        *(uint2*)(Wth + (size_t)n*D_ + d0 + dc*4) = hh.v;
        *(uint2*)(Wtl + (size_t)n*D_ + d0 + dc*4) = ll.v;
    }
}

// ---- QKV GEMM: qkv[t][col] = x[t][:]·Wt[col][:], col in [0,3072) ----
// PS=true: A staged from pre-split xh/xl via GLD16 (pure async, zero VALU/ds_write
// in loop); q written pre-split. PS=false: round-4 path (bit-identical output).
template<bool PS>
__global__ __launch_bounds__(256) void gemm_qkv(const float* __restrict__ x,
                                                const u16* __restrict__ xh, const u16* __restrict__ xl,
                                                const u16* __restrict__ Wth,
                                                const u16* __restrict__ Wtl,
                                                float* __restrict__ qo,
                                                u16* __restrict__ qho, u16* __restrict__ qlo,
                                                u16* __restrict__ kho, u16* __restrict__ klo,
                                                u16* __restrict__ vth, u16* __restrict__ vtl)
{
    __shared__ u16 Ash[128*32], Asl[128*32];
    __shared__ u16 Bsh[128*32], Bsl[128*32];
    const int n0 = blockIdx.x*128, m0 = blockIdx.y*128;
    const int t = threadIdx.x;
    const int w = t>>6, lane = t&63, quad = lane>>4, l16 = lane&15;
    const int wm = (w>>1)*64, wn = (w&1)*64;
    f32x4 acc[4][4];
    #pragma unroll
    for (int i=0;i<4;++i)
        #pragma unroll
        for (int j=0;j<4;++j) acc[i][j] = (f32x4){0.f,0.f,0.f,0.f};
    for (int kt=0; kt<32; ++kt){
        const int k0 = kt*32;
        #pragma unroll
        for (int i=0;i<2;++i){           // B: async 16B chunks, pre-swizzled source
            int ci = t + 256*i;
            int row = ci>>2, c = ci&3;
            int cs = c ^ FCHK(row);
            GLD16(Wth + (size_t)(n0+row)*D_ + k0 + cs*8, Bsh + ci*8);
            GLD16(Wtl + (size_t)(n0+row)*D_ + k0 + cs*8, Bsl + ci*8);
        }
        if constexpr(PS){
            #pragma unroll
            for (int i=0;i<2;++i){       // A: async too (pre-split x)
                int ci = t + 256*i;
                int row = ci>>2, c = ci&3;
                int cs = c ^ FCHK(row);
                GLD16(xh + (size_t)(m0+row)*D_ + k0 + cs*8, Ash + ci*8);
                GLD16(xl + (size_t)(m0+row)*D_ + k0 + cs*8, Asl + ci*8);
            }
        } else {
            #pragma unroll
            for (int i=0;i<4;++i){       // A: f32 load + split, swizzled ds_write
                int ci = t + 256*i;
                int row = ci>>3, c4 = ci&7;
                float4 av = *(const float4*)(x + (size_t)(m0+row)*D_ + k0 + c4*4);
                U4 hh, ll;
                split2(av.x, hh.s[0], ll.s[0]); split2(av.y, hh.s[1], ll.s[1]);
                split2(av.z, hh.s[2], ll.s[2]); split2(av.w, hh.s[3], ll.s[3]);
                int off = row*32 + ((((c4>>1) ^ FCHK(row))<<3) | ((c4&1)<<2));
                *(uint2*)(Ash + off) = hh.v;
                *(uint2*)(Asl + off) = ll.v;
            }
        }
        __syncthreads();
        short8 afh[4], afl[4], bfh[4], bfl[4];
        #pragma unroll
        for (int mi=0;mi<4;++mi){
            const int rr = wm+mi*16+l16;
            const int off = rr*32 + ((quad ^ FCHK(rr))<<3);
            afh[mi] = *(const short8*)(Ash + off);
            afl[mi] = *(const short8*)(Asl + off);
        }
        #pragma unroll
        for (int ni=0;ni<4;++ni){
            const int rr = wn+ni*16+l16;
            const int off = rr*32 + ((quad ^ FCHK(rr))<<3);
            bfh[ni] = *(const short8*)(Bsh + off);
            bfl[ni] = *(const short8*)(Bsl + off);
        }
        #pragma unroll
        for (int mi=0;mi<4;++mi)
            #pragma unroll
            for (int ni=0;ni<4;++ni){
                acc[mi][ni] = __builtin_amdgcn_mfma_f32_16x16x32_bf16(afh[mi], bfh[ni], acc[mi][ni], 0,0,0);
                acc[mi][ni] = __builtin_amdgcn_mfma_f32_16x16x32_bf16(afh[mi], bfl[ni], acc[mi][ni], 0,0,0);
                acc[mi][ni] = __builtin_amdgcn_mfma_f32_16x16x32_bf16(afl[mi], bfh[ni], acc[mi][ni], 0,0,0);
            }
        __syncthreads();
    }
    const int z = n0 >> 10;              // block-uniform (128 | 1024)
    if (z <= 1){
        if constexpr(PS){
            u16* dh = z ? kho : qho;
            u16* dl = z ? klo : qlo;
            #pragma unroll
            for (int ni=0;ni<4;++ni){
                const int nloc = (n0 & 1023) + wn + ni*16 + l16;
                #pragma unroll
                for (int mi=0;mi<4;++mi){
                    const int row = m0 + wm + mi*16 + quad*4;
                    #pragma unroll
                    for (int r=0;r<4;++r){
                        u16 hh, ll; split2(acc[mi][ni][r], hh, ll);
                        dh[(size_t)(row+r)*D_ + nloc] = hh;
                        dl[(size_t)(row+r)*D_ + nloc] = ll;
                    }
                }
            }
        } else {
            if (z == 0){
                #pragma unroll
                for (int ni=0;ni<4;++ni){
                    const int nloc = (n0 & 1023) + wn + ni*16 + l16;
                    #pragma unroll
                    for (int mi=0;mi<4;++mi){
                        const int row = m0 + wm + mi*16 + quad*4;
                        #pragma unroll
                        for (int r=0;r<4;++r)
                            qo[(size_t)(row+r)*D_ + nloc] = acc[mi][ni][r];
                    }
                }
            } else {
                #pragma unroll
                for (int ni=0;ni<4;++ni){
                    const int nloc = (n0 & 1023) + wn + ni*16 + l16;
                    #pragma unroll
                    for (int mi=0;mi<4;++mi){
                        const int row = m0 + wm + mi*16 + quad*4;
                        #pragma unroll
                        for (int r=0;r<4;++r){
                            u16 hh, ll; split2(acc[mi][ni][r], hh, ll);
                            kho[(size_t)(row+r)*D_ + nloc] = hh;
                            klo[(size_t)(row+r)*D_ + nloc] = ll;
                        }
                    }
                }
            }
        }
    } else {
        #pragma unroll
        for (int ni=0;ni<4;++ni){
            const int nloc = (n0 & 1023) + wn + ni*16 + l16;
            const int hloc = nloc>>6, e = nloc&63;
            #pragma unroll
            for (int mi=0;mi<4;++mi){
                const int rowb = m0 + wm + mi*16 + quad*4;   // multiple of 4
                const int bidx = rowb >> 11, tloc = rowb & 2047;
                U4 hh, ll;
                #pragma unroll
                for (int r=0;r<4;++r) split2(acc[mi][ni][r], hh.s[r], ll.s[r]);
                const size_t adr = ((size_t)((bidx*16 + hloc)*64 + e))*T_ + tloc;
                *(uint2*)(vth + adr) = hh.v;
                *(uint2*)(vtl + adr) = ll.v;
            }
        }
    }
}

// ---- causal flash attention; paired q-tiles (qi=15-x then x), 512 blocks,
// 2 blocks/CU, XCD-grouped K/V sharing; (512,2) launch bounds.
// ROUND-6 FIX: prefetch ISSUE moved AFTER the second __syncthreads. hipcc's
// __syncthreads emits s_waitcnt vmcnt(0) before s_barrier (barrier drain), so
// issuing loads BETWEEN the barriers exposed full L2/HBM latency every kv-tile
// (all 8 waves in lockstep). Issuing after barrier-2 lets loads fly under the
// whole QK/softmax/PV compute; they are drained for free at the next top
// barrier, ~2000 cycles later. ----
template<bool PS>
__global__ __launch_bounds__(512, 2) void attn(const float* __restrict__ qf,
                                            const u16* __restrict__ qh, const u16* __restrict__ ql,
                                            const u16* __restrict__ kh, const u16* __restrict__ kl,
                                            const u16* __restrict__ vth, const u16* __restrict__ vtl,
                                            float* __restrict__ att,
                                            u16* __restrict__ atth, u16* __restrict__ attl)
{
    __shared__ u16 Ksh[64*64], Ksl[64*64];   // [kv][e], swizzled (16 KB)
    __shared__ u16 Vsh[64*64], Vsl[64*64];   // [e][kv], swizzled (16 KB)
    __shared__ u16 Pb[8*32*64];              // per-wave [32][64]: hi rows 0-15, lo rows 16-31 (32 KB)
    const int x = blockIdx.y & 7;            // q-pair index (XCD-grouped remap)
    const int bh = (blockIdx.x << 3) | (blockIdx.y >> 3);
    const int b = bh >> 4, h = bh & 15;
    const int t = threadIdx.x;
    const int w = t>>6, lane = t&63, quad = lane>>4, l16 = lane&15;

    u16* Pm = Pb + w*2048;

    // staging geometry: 512 threads = 64 rows x 8 chunks, 1 uint4/thread/array
    const int srow = t>>3, sc = t&7;
    const int slo = swz(srow, sc*8);
    uint4 pkh, pkl, pvh, pvl;                // register prefetch
    {   // prime kv tile 0 (segment 0)
        const size_t gk = ((size_t)(b*T_ + srow))*D_ + h*64 + sc*8;
        pkh = *(const uint4*)(kh + gk);
        pkl = *(const uint4*)(kl + gk);
        const size_t gv = ((size_t)(bh*64 + srow))*T_ + sc*8;
        pvh = *(const uint4*)(vth + gv);
        pvl = *(const uint4*)(vtl + gv);
    }

    #pragma unroll 1
    for (int seg=0; seg<2; ++seg){
        const int qi = seg ? x : (15 - x);   // heavy segment first
        const int qrow = qi*128 + w*16;      // wave's absolute q base

        short8 qh_[2], ql_[2];
        if constexpr(PS){
            const size_t qb = ((size_t)(b*T_ + qrow + l16))*D_ + h*64;
            #pragma unroll
            for (int ks=0;ks<2;++ks){
                qh_[ks] = *(const short8*)(qh + qb + ks*32 + quad*8);
                ql_[ks] = *(const short8*)(ql + qb + ks*32 + quad*8);
            }
        } else {
            const float* qp = qf + ((size_t)(b*T_ + qrow + l16))*D_ + h*64;
            #pragma unroll
            for (int ks=0;ks<2;++ks){
                float4 a0 = *(const float4*)(qp + ks*32 + quad*8);
                float4 a1 = *(const float4*)(qp + ks*32 + quad*8 + 4);
                S8 hh, ll;
                split2(a0.x, hh.s[0], ll.s[0]); split2(a0.y, hh.s[1], ll.s[1]);
                split2(a0.z, hh.s[2], ll.s[2]); split2(a0.w, hh.s[3], ll.s[3]);
                split2(a1.x, hh.s[4], ll.s[4]); split2(a1.y, hh.s[5], ll.s[5]);
                split2(a1.z, hh.s[6], ll.s[6]); split2(a1.w, hh.s[7], ll.s[7]);
                qh_[ks] = hh.v; ql_[ks] = ll.v;
            }
        }
        f32x4 o[4];
        #pragma unroll
        for (int i=0;i<4;++i) o[i] = (f32x4){0.f,0.f,0.f,0.f};
        float m_i[4], l_i[4];
        #pragma unroll
        for (int r=0;r<4;++r){ m_i[r] = -INFINITY; l_i[r] = 0.f; }

        const int kvT = 2*qi + 2;
        for (int kvt=0; kvt<kvT; ++kvt){
            __syncthreads();                 // prev-iter readers done; drains in-flight prefetch
            *(uint4*)(Ksh + slo) = pkh;
            *(uint4*)(Ksl + slo) = pkl;
            *(uint4*)(Vsh + slo) = pvh;
            *(uint4*)(Vsl + slo) = pvl;
            __syncthreads();                 // staged tile visible to all waves

            // issue next-tile prefetch AFTER the barrier: loads overlap the whole
            // tile compute instead of being drained by the barrier's vmcnt(0).
            const int nk = (kvt+1 < kvT) ? (kvt+1) : ((seg==0) ? 0 : -1);
            if (nk >= 0){
                const size_t gk = ((size_t)(b*T_ + nk*64 + srow))*D_ + h*64 + sc*8;
                pkh = *(const uint4*)(kh + gk);
                pkl = *(const uint4*)(kl + gk);
                const size_t gv = ((size_t)(bh*64 + srow))*T_ + nk*64 + sc*8;
                pvh = *(const uint4*)(vth + gv);
                pvl = *(const uint4*)(vtl + gv);
            }

            float s[4][4];
            __builtin_amdgcn_s_setprio(1);
            #pragma unroll
            for (int ni=0;ni<4;++ni){
                f32x4 sa = (f32x4){0.f,0.f,0.f,0.f};
                const int row = ni*16 + l16;
                #pragma unroll
                for (int ks=0;ks<2;++ks){
                    const int co = swz(row, ks*32 + quad*8);
                    short8 k8h = *(const short8*)(Ksh + co);
                    short8 k8l = *(const short8*)(Ksl + co);
                    sa = __builtin_amdgcn_mfma_f32_16x16x32_bf16(qh_[ks], k8h, sa, 0,0,0);
                    sa = __builtin_amdgcn_mfma_f32_16x16x32_bf16(qh_[ks], k8l, sa, 0,0,0);
                    sa = __builtin_amdgcn_mfma_f32_16x16x32_bf16(ql_[ks], k8h, sa, 0,0,0);
                }
                #pragma unroll
                for (int r=0;r<4;++r) s[ni][r] = sa[r]*0.125f;
            }
            __builtin_amdgcn_s_setprio(0);
            // causal mask iff tile max col can exceed wave MIN row
            if (kvt*64 + 63 > qrow){
                #pragma unroll
                for (int ni=0;ni<4;++ni){
                    const int colabs = kvt*64 + ni*16 + l16;
                    #pragma unroll
                    for (int r=0;r<4;++r){
                        const int rowabs = qrow + quad*4 + r;
                        if (colabs > rowabs) s[ni][r] = -INFINITY;
                    }
                }
            }
            float alpha[4];
            #pragma unroll
            for (int r=0;r<4;++r){
                float rm = fmaxf(fmaxf(s[0][r],s[1][r]), fmaxf(s[2][r],s[3][r]));
                rm = fmaxf(rm, DPPMV(rm, 0xB1));   // quad_perm xor1
                rm = fmaxf(rm, DPPMV(rm, 0x4E));   // quad_perm xor2
                rm = fmaxf(rm, DPPMV(rm, 0x124));  // row_ror:4
                rm = fmaxf(rm, DPPMV(rm, 0x128));  // row_ror:8
                const float mnew = fmaxf(m_i[r], rm);
                alpha[r] = __expf(m_i[r] - mnew);
                m_i[r] = mnew;
                #pragma unroll
                for (int ni=0;ni<4;++ni) s[ni][r] = __expf(s[ni][r] - mnew);  // in place
                float rs = s[0][r]+s[1][r]+s[2][r]+s[3][r];
                rs += DPPMV(rs, 0xB1);
                rs += DPPMV(rs, 0x4E);
                rs += DPPMV(rs, 0x124);
                rs += DPPMV(rs, 0x128);
                l_i[r] = l_i[r]*alpha[r] + rs;
            }
            #pragma unroll
            for (int ni=0;ni<4;++ni)
                #pragma unroll
                for (int r=0;r<4;++r) o[ni][r] *= alpha[r];

            // ---- P: split once, write hi rows 0-15 + lo rows 16-31, one wait, read both ----
            u16 ph[4][4], pl[4][4];
            #pragma unroll
            for (int ni=0;ni<4;++ni)
                #pragma unroll
                for (int r=0;r<4;++r)
                    split2(s[ni][r], ph[ni][r], pl[ni][r]);
            #pragma unroll
            for (int ni=0;ni<4;++ni)
                #pragma unroll
                for (int r=0;r<4;++r){
                    Pm[swz(quad*4+r,      ni*16 + l16)] = ph[ni][r];
                    Pm[swz(16 + quad*4+r, ni*16 + l16)] = pl[ni][r];
                }
            __asm__ volatile("s_waitcnt lgkmcnt(0)" ::: "memory");
            short8 pah[2], pal[2];
            #pragma unroll
            for (int ks=0;ks<2;++ks){
                pah[ks] = *(const short8*)(Pm + swz(l16,      ks*32 + quad*8));
                pal[ks] = *(const short8*)(Pm + swz(16 + l16, ks*32 + quad*8));
            }

            __builtin_amdgcn_s_setprio(1);
            #pragma unroll
            for (int ni=0;ni<4;++ni){
                const int row = ni*16 + l16;
                #pragma unroll
                for (int ks=0;ks<2;++ks){
                    const int co = swz(row, ks*32 + quad*8);
                    short8 v8h = *(const short8*)(Vsh + co);
                    short8 v8l = *(const short8*)(Vsl + co);
                    o[ni] = __builtin_amdgcn_mfma_f32_16x16x32_bf16(pah[ks], v8h, o[ni], 0,0,0);
                    o[ni] = __builtin_amdgcn_mfma_f32_16x16x32_bf16(pah[ks], v8l, o[ni], 0,0,0);
                    o[ni] = __builtin_amdgcn_mfma_f32_16x16x32_bf16(pal[ks], v8h, o[ni], 0,0,0);
                }
            }
            __builtin_amdgcn_s_setprio(0);
        }
        const size_t ob = (size_t)(b*T_ + qrow);
        #pragma unroll
        for (int ni=0;ni<4;++ni){
            const int col = h*64 + ni*16 + l16;
            #pragma unroll
            for (int r=0;r<4;++r){
                const float v = o[ni][r] / l_i[r];
                const size_t idx = (ob + quad*4 + r)*D_ + col;
                if constexpr(PS){
                    u16 hh, ll; split2(v, hh, ll);
                    atth[idx] = hh; attl[idx] = ll;
                } else {
                    att[idx] = v;
                }
            }
        }
    }
}

// ---- out-proj GEMM. PS=true: A=atth/attl, B=Wph/Wpl, all GLD16.
// PS=false: round-4 f32-staged path. ----
template<bool PS>
__global__ __launch_bounds__(256) void gemm_bt(const float* __restrict__ A,
                                               const u16* __restrict__ Ath, const u16* __restrict__ Atl,
                                               const float* __restrict__ Bt,
                                               const u16* __restrict__ Bth, const u16* __restrict__ Btl,
                                               float* __restrict__ C,
                                               const float* __restrict__ bias,
                                               int M, int N, int K)
{
    __shared__ u16 Ash[128*32], Asl[128*32];
    __shared__ u16 Bsh[128*32], Bsl[128*32];
    const int n0 = blockIdx.x*128, m0 = blockIdx.y*128;
    const int t = threadIdx.x;
    const int w = t>>6, lane = t&63, quad = lane>>4, l16 = lane&15;
    const int wm = (w>>1)*64, wn = (w&1)*64;
    f32x4 acc[4][4];
    #pragma unroll
    for (int i=0;i<4;++i)
        #pragma unroll
        for (int j=0;j<4;++j) acc[i][j] = (f32x4){0.f,0.f,0.f,0.f};
    const int kT = K >> 5;
    for (int kt=0; kt<kT; ++kt){
        const int k0 = kt*32;
        if constexpr(PS){
            #pragma unroll
            for (int i=0;i<2;++i){
                int ci = t + 256*i;
                int row = ci>>2, c = ci&3;
                int cs = c ^ FCHK(row);
                GLD16(Ath + (size_t)(m0+row)*K + k0 + cs*8, Ash + ci*8);
                GLD16(Atl + (size_t)(m0+row)*K + k0 + cs*8, Asl + ci*8);
                GLD16(Bth + (size_t)(n0+row)*K + k0 + cs*8, Bsh + ci*8);
                GLD16(Btl + (size_t)(n0+row)*K + k0 + cs*8, Bsl + ci*8);
            }
        } else {
            #pragma unroll
            for (int i=0;i<4;++i){
                int ci = t + 256*i;
                int row = ci>>3, c4 = ci&7;
                float4 av = *(const float4*)(A  + (size_t)(m0+row)*K + k0 + c4*4);
                float4 bv = *(const float4*)(Bt + (size_t)(n0+row)*K + k0 + c4*4);
                U4 ah, al, bh, bl;
                split2(av.x, ah.s[0], al.s[0]); split2(av.y, ah.s[1], al.s[1]);
                split2(av.z, ah.s[2], al.s[2]); split2(av.w, ah.s[3], al.s[3]);
                split2(bv.x, bh.s[0], bl.s[0]); split2(bv.y, bh.s[1], bl.s[1]);
                split2(bv.z, bh.s[2], bl.s[2]); split2(bv.w, bh.s[3], bl.s[3]);
                int off = row*32 + ((((c4>>1) ^ FCHK(row))<<3) | ((c4&1)<<2));
                *(uint2*)(Ash + off) = ah.v;
                *(uint2*)(Asl + off) = al.v;
                *(uint2*)(Bsh + off) = bh.v;
                *(uint2*)(Bsl + off) = bl.v;
            }
        }
        __syncthreads();
        short8 afh[4], afl[4], bfh[4], bfl[4];
        #pragma unroll
        for (int mi=0;mi<4;++mi){
            const int rr = wm+mi*16+l16;
            const int off = rr*32 + ((quad ^ FCHK(rr))<<3);
            afh[mi] = *(const short8*)(Ash + off);
            afl[mi] = *(const short8*)(Asl + off);
        }
        #pragma unroll
        for (int ni=0;ni<4;++ni){
            const int rr = wn+ni*16+l16;
            const int off = rr*32 + ((quad ^ FCHK(rr))<<3);
            bfh[ni] = *(const short8*)(Bsh + off);
            bfl[ni] = *(const short8*)(Bsl + off);
        }
        #pragma unroll
        for (int mi=0;mi<4;++mi)
            #pragma unroll
            for (int ni=0;ni<4;++ni){
                acc[mi][ni] = __builtin_amdgcn_mfma_f32_16x16x32_bf16(afh[mi], bfh[ni], acc[mi][ni], 0,0,0);
                acc[mi][ni] = __builtin_amdgcn_mfma_f32_16x16x32_bf16(afh[mi], bfl[ni], acc[mi][ni], 0,0,0);
                acc[mi][ni] = __builtin_amdgcn_mfma_f32_16x16x32_bf16(afl[mi], bfh[ni], acc[mi][ni], 0,0,0);
            }
        __syncthreads();
    }
    #pragma unroll
    for (int ni=0;ni<4;++ni){
        const int col = n0 + wn + ni*16 + l16;
        const float bv = bias ? bias[col] : 0.f;
        #pragma unroll
        for (int mi=0;mi<4;++mi){
            const int row = m0 + wm + mi*16 + quad*4;
            #pragma unroll
            for (int r=0;r<4;++r)
                C[(size_t)(row+r)*N + col] = acc[mi][ni][r] + bv;
        }
    }
}

extern "C" void kernel_launch(void* const* d_in, const int* in_sizes, int n_in,
                              void* d_out, int out_size, void* d_ws, size_t ws_size,
                              hipStream_t stream)
{
    const float* x  = (const float*)d_in[0];
    const float* Wq = (const float*)d_in[1];
    const float* Wk = (const float*)d_in[2];
    const float* Wv = (const float*)d_in[3];
    const float* Wp = (const float*)d_in[4];
    const float* bp = (const float*)d_in[5];
    float* out = (float*)d_out;

    const size_t NE = (size_t)BT*D_;                  // 8.39M elems
    const size_t NEED = (10*NE + 2*(size_t)D_*D_)*2;  // 171,966,464 B

    if (ws_size >= NEED){
        // pre-split layout (172 MB)
        u16* xh   = (u16*)d_ws;
        u16* xl   = xh + NE;
        u16* qh   = xl + NE;
        u16* ql   = qh + NE;
        u16* kh   = ql + NE;
        u16* kl   = kh + NE;
        u16* vth  = kl + NE;
        u16* vtl  = vth + NE;
        u16* atth = vtl + NE;                 // [BT][1024] split pair
        u16* attl = atth + NE;
        u16* Wph  = attl + NE;                // [1024][1024] split pair
        u16* Wpl  = Wph + (size_t)D_*D_;
        // Wt aliases atth region (12.6 MB <= 16.8 MB): dead before attn writes atth
        u16* Wth  = atth;
        u16* Wtl  = Wth + (size_t)3072*D_;

        split_f32<<<1024, 256, 0, stream>>>(x,  xh,  xl,  (int)(NE/8));
        split_f32<<<512,  256, 0, stream>>>(Wp, Wph, Wpl, (int)(((size_t)D_*D_)/8));
        pack_w   <<<dim3(16,16,3), 256, 0, stream>>>(Wq, Wk, Wv, Wth, Wtl);
        gemm_qkv<true><<<dim3(24, BT/128), 256, 0, stream>>>(x, xh, xl, Wth, Wtl,
                                                             nullptr, qh, ql, kh, kl, vth, vtl);
        attn<true><<<dim3(T_/256, B_*H_), 512, 0, stream>>>(nullptr, qh, ql, kh, kl, vth, vtl,
                                                            nullptr, atth, attl);
        gemm_bt<true><<<dim3(8, BT/128), 256, 0, stream>>>(nullptr, atth, attl,
                                                           nullptr, Wph, Wpl,
                                                           out, bp, BT, D_, D_);
    } else {
        // round-4 fallback layout (134.2 MB)
        float* q   = (float*)d_ws;
        u16*  kh   = (u16*)(q + NE);
        u16*  kl   = kh + NE;
        u16*  vth  = kl + NE;
        u16*  vtl  = vth + NE;
        float* att = (float*)(vtl + NE);
        u16*  Wth  = (u16*)att;
        u16*  Wtl  = Wth + (size_t)3072*D_;

        pack_w   <<<dim3(16,16,3), 256, 0, stream>>>(Wq, Wk, Wv, Wth, Wtl);
        gemm_qkv<false><<<dim3(24, BT/128), 256, 0, stream>>>(x, nullptr, nullptr, Wth, Wtl,
                                                              q, nullptr, nullptr, kh, kl, vth, vtl);
        attn<false><<<dim3(T_/256, B_*H_), 512, 0, stream>>>(q, nullptr, nullptr, kh, kl, vth, vtl,
                                                             att, nullptr, nullptr);
        gemm_bt<false><<<dim3(8, BT/128), 256, 0, stream>>>(att, nullptr, nullptr,
                                                            Wp, nullptr, nullptr,
                                                            out, bp, BT, D_, D_);
    }
}